// Round 1
// baseline (616.848 us; speedup 1.0000x reference)
//
#include <hip/hip_runtime.h>
#include <hip/hip_bf16.h>
#include <float.h>

#define PI_D 3.14159265358979323846

// ---------------- problem constants ----------------
#define LWAV 240000
#define TFR  751            // frames per batch
#define BATCH 16
#define MROWS (BATCH * TFR) // 12016
#define NMEL 128

// ---------------- workspace layout (bytes) ----------------
#define OFF_WIN   0u            // 1024 f32
#define OFF_TW    4096u         // 256 float2
#define OFF_UTW   6144u         // 513 float2 (pad to 10496)
#define OFF_FB    10496u        // 513*128 f32
#define OFF_WB1   273152u       // 384*256 f32
#define OFF_WB2   666368u       // 768*512 f32
#define OFF_C2    2239232u      // 4*1024 f32
#define OFF_LM    2255616u      // 12016*128 f32
#define OFF_H     8407808u      // 12016*256 f32
#define OFF_FE    20712192u     // 12016*512 f32
#define WS_NEEDED 45320960u

// ---------------- setup kernels ----------------
__global__ void k_setup_tab(float* __restrict__ win, float2* __restrict__ tw,
                            float2* __restrict__ utw) {
  int t = threadIdx.x;  // 1024 threads
  if (t < 1024) {
    double v = 0.5 * (1.0 - cos(2.0 * PI_D * (double)t / 1024.0));
    win[t] = (float)v;
  }
  if (t < 256) {
    double a = -2.0 * PI_D * (double)t / 512.0;
    tw[t] = make_float2((float)cos(a), (float)sin(a));
  }
  if (t < 513) {
    double a = -2.0 * PI_D * (double)t / 1024.0;
    utw[t] = make_float2((float)cos(a), (float)sin(a));
  }
}

__device__ __forceinline__ double fpt_d(int j) {
  double melmax = 2595.0 * log10(1.0 + 12000.0 / 700.0);
  double mp = melmax * (double)j / 129.0;
  return 700.0 * (pow(10.0, mp / 2595.0) - 1.0);
}

__global__ void k_setup_fb(float* __restrict__ FB) {
  int f = blockIdx.x;   // 0..512
  int m = threadIdx.x;  // 0..127
  double freq = 12000.0 * (double)f / 512.0;
  double f0 = fpt_d(m), f1 = fpt_d(m + 1), f2 = fpt_d(m + 2);
  double down = (freq - f0) / (f1 - f0);
  double up = (f2 - freq) / (f2 - f1);
  double v = fmin(down, up);
  v = fmax(0.0, v);
  FB[f * NMEL + m] = (float)v;
}

// wt[(dt*C+i)*O + o] = w[(o*C+i)*3 + dt]
__global__ void k_wt(const float* __restrict__ w, float* __restrict__ wt,
                     int O, int C) {
  int idx = blockIdx.x * 256 + threadIdx.x;
  int total = O * C * 3;
  if (idx >= total) return;
  int o = idx % O;
  int rest = idx / O;
  int i = rest % C;
  int dt = rest / C;
  wt[(dt * C + i) * O + o] = w[(o * C + i) * 3 + dt];
}

__global__ void k_c2(const float* __restrict__ cb, float* __restrict__ c2) {
  int v = blockIdx.x * 256 + threadIdx.x;  // 4096 rows
  if (v >= 4096) return;
  const float* r = cb + (size_t)v * 128;
  float s = 0.f;
#pragma unroll 8
  for (int i = 0; i < 128; ++i) s = fmaf(r[i], r[i], s);
  c2[v] = s;
}

// ---------------- log-mel kernel ----------------
__device__ __forceinline__ float powspec(const float2* Z, const float2* __restrict__ utw,
                                         int k) {
  float2 Zk = Z[k & 511];
  float2 Zm = Z[(512 - k) & 511];
  float2 ut = utw[k];
  float fer = 0.5f * (Zk.x + Zm.x);
  float fei = 0.5f * (Zk.y - Zm.y);
  float fo_r = 0.5f * (Zk.y + Zm.y);
  float fo_i = -0.5f * (Zk.x - Zm.x);
  float xr = fer + ut.x * fo_r - ut.y * fo_i;
  float xi = fei + ut.x * fo_i + ut.y * fo_r;
  return xr * xr + xi * xi;
}

__global__ __launch_bounds__(256) void k_logmel(
    const float* __restrict__ wav, const float* __restrict__ win,
    const float2* __restrict__ tw, const float2* __restrict__ utw,
    const float* __restrict__ FB, float* __restrict__ lm) {
  __shared__ float2 bufA[512];
  __shared__ float2 bufB[512];
  __shared__ float p[513];
  __shared__ float partial[128];

  const int fr = blockIdx.x;       // 0..12015
  const int b = fr / TFR;
  const int t = fr - b * TFR;
  const int tid = threadIdx.x;
  const float* wv = wav + (size_t)b * LWAV;

  // load 1024 samples with reflect padding, window, pack complex
  const int base = t * 320 - 512;
  float s[4];
#pragma unroll
  for (int q = 0; q < 4; ++q) {
    int n = tid * 4 + q;
    int j = base + n;
    j = (j < 0) ? -j : j;
    j = (j >= LWAV) ? (2 * LWAV - 2 - j) : j;
    s[q] = wv[j] * win[n];
  }
  bufA[tid * 2] = make_float2(s[0], s[1]);
  bufA[tid * 2 + 1] = make_float2(s[2], s[3]);
  __syncthreads();

  // 512-pt Stockham DIF FFT, 9 stages, 1 butterfly/thread/stage
  float2* src = bufA;
  float2* dst = bufB;
#pragma unroll
  for (int st = 0; st < 9; ++st) {
    float2 a = src[tid];
    float2 c = src[tid + 256];
    float2 w = tw[(tid >> st) << st];
    float2 sum = make_float2(a.x + c.x, a.y + c.y);
    float2 dif = make_float2(a.x - c.x, a.y - c.y);
    float2 wd = make_float2(w.x * dif.x - w.y * dif.y, w.x * dif.y + w.y * dif.x);
    int d0 = tid + ((tid >> st) << st);
    dst[d0] = sum;
    dst[d0 + (1 << st)] = wd;
    __syncthreads();
    float2* tmp = src; src = dst; dst = tmp;
  }
  const float2* Z = src;

  // real-FFT unpack -> power spectrum (513 bins)
  p[tid] = powspec(Z, utw, tid);
  p[tid + 256] = powspec(Z, utw, tid + 256);
  if (tid == 0) p[512] = powspec(Z, utw, 512);
  __syncthreads();

  // mel projection + log, f-range split across thread halves
  {
    int mm = tid & 127;
    int half = tid >> 7;
    int f0 = half ? 257 : 0;
    int f1 = half ? 513 : 257;
    float acc = 0.f;
    const float* fb = FB + mm;
    for (int f = f0; f < f1; ++f) acc = fmaf(p[f], fb[(size_t)f * NMEL], acc);
    if (half) partial[mm] = acc;
    __syncthreads();
    if (!half) {
      float tot = acc + partial[mm];
      lm[(size_t)fr * NMEL + mm] = logf(fmaxf(tot, 1e-5f));
    }
  }
}

// ---------------- conv-as-GEMM kernel ----------------
// out[m][n] = act( bias[n] + sum_k A[m][k] * wt[k][n] ),  k = dt*C + i,
// A[m][k] = in[(m + dt - 1)][i] with per-batch zero padding at t edges.
template <int C, int N, bool GELU>
__global__ __launch_bounds__(256) void k_conv(const float* __restrict__ in,
                                              const float* __restrict__ wt,
                                              const float* __restrict__ bias,
                                              float* __restrict__ out) {
  constexpr int K = 3 * C;
  __shared__ float At[32 * 64];  // [kc][m]
  __shared__ float Bt[32 * 64];  // [kc][n]
  const int m0 = blockIdx.x * 64;
  const int n0 = blockIdx.y * 64;
  const int tid = threadIdx.x;
  const int tm = tid >> 4, tn = tid & 15;

  float acc[4][4] = {};

  const int ml = tid >> 2;          // staging row 0..63
  const int fi0 = tid & 3;
  const int mload = m0 + ml;
  const int bql = mload / TFR;
  const int tql = mload - bql * TFR;

  for (int k0 = 0; k0 < K; k0 += 32) {
    const int dt = k0 / C;
    const int i0 = k0 - dt * C;
    // stage A (transposed)
    {
      const int tt = tql + dt - 1;
      const bool ok = (mload < MROWS) && (tt >= 0) && (tt < TFR);
      const float* rp = in + (size_t)(mload + dt - 1) * C + i0;
#pragma unroll
      for (int h = 0; h < 2; ++h) {
        const int fi = fi0 + h * 4;
        float4 v = ok ? *(const float4*)(rp + fi * 4) : make_float4(0.f, 0.f, 0.f, 0.f);
        At[(fi * 4 + 0) * 64 + ml] = v.x;
        At[(fi * 4 + 1) * 64 + ml] = v.y;
        At[(fi * 4 + 2) * 64 + ml] = v.z;
        At[(fi * 4 + 3) * 64 + ml] = v.w;
      }
    }
    // stage B
    {
#pragma unroll
      for (int h = 0; h < 2; ++h) {
        const int e = tid + h * 256;  // float4 id 0..511
        const int kc = e >> 4;
        const int nf = e & 15;
        float4 v = *(const float4*)(wt + (size_t)(k0 + kc) * N + n0 + nf * 4);
        *(float4*)&Bt[kc * 64 + nf * 4] = v;
      }
    }
    __syncthreads();
#pragma unroll
    for (int kc = 0; kc < 32; ++kc) {
      float4 a = *(const float4*)&At[kc * 64 + tm * 4];
      float4 bv = *(const float4*)&Bt[kc * 64 + tn * 4];
      float av[4] = {a.x, a.y, a.z, a.w};
      float bb[4] = {bv.x, bv.y, bv.z, bv.w};
#pragma unroll
      for (int r = 0; r < 4; ++r)
#pragma unroll
        for (int c = 0; c < 4; ++c) acc[r][c] = fmaf(av[r], bb[c], acc[r][c]);
    }
    __syncthreads();
  }

#pragma unroll
  for (int r = 0; r < 4; ++r) {
    const int m = m0 + tm * 4 + r;
    if (m >= MROWS) continue;
    float4 o;
    float* ov = (float*)&o;
#pragma unroll
    for (int c = 0; c < 4; ++c) {
      float v = acc[r][c] + bias[n0 + tn * 4 + c];
      if (GELU) v = 0.5f * v * (1.0f + erff(v * 0.7071067811865476f));
      ov[c] = v;
    }
    *(float4*)(out + (size_t)m * N + n0 + tn * 4) = o;
  }
}

// ---------------- VQ kernel: distances + argmin ----------------
__global__ __launch_bounds__(256) void k_vq(const float* __restrict__ feats,
                                            const float* __restrict__ cbs,
                                            const float* __restrict__ c2,
                                            int* __restrict__ out) {
  __shared__ float At[128 * 64];  // [kc][m]
  __shared__ float Bt[32 * 64];   // [kc][n]
  __shared__ float x2s[64];
  __shared__ float redD[64 * 16];
  __shared__ int redI[64 * 16];

  const int m0 = blockIdx.x * 64;
  const int cb = blockIdx.y;
  const int tid = threadIdx.x;
  const int tm = tid >> 4, tn = tid & 15;

  // stage A: feats[m][cb*128 .. +128), transposed
  {
    const int ml = tid >> 2;
    const int fi0 = tid & 3;
    const int m = m0 + ml;
    const bool ok = (m < MROWS);
    const float* rp = feats + (size_t)m * 512 + cb * 128;
#pragma unroll
    for (int h = 0; h < 8; ++h) {
      const int fi = fi0 + h * 4;
      float4 v = ok ? *(const float4*)(rp + fi * 4) : make_float4(0.f, 0.f, 0.f, 0.f);
      At[(fi * 4 + 0) * 64 + ml] = v.x;
      At[(fi * 4 + 1) * 64 + ml] = v.y;
      At[(fi * 4 + 2) * 64 + ml] = v.z;
      At[(fi * 4 + 3) * 64 + ml] = v.w;
    }
  }
  __syncthreads();
  if (tid < 64) {
    float s = 0.f;
#pragma unroll 8
    for (int kc = 0; kc < 128; ++kc) {
      float a = At[kc * 64 + tid];
      s = fmaf(a, a, s);
    }
    x2s[tid] = s;
  }

  float best[4] = {FLT_MAX, FLT_MAX, FLT_MAX, FLT_MAX};
  int bidx[4] = {0, 0, 0, 0};
  const float* cbbase = cbs + (size_t)cb * 1024 * 128;
  const float* c2b = c2 + cb * 1024;

  for (int nc = 0; nc < 16; ++nc) {
    float acc[4][4] = {};
    for (int ks = 0; ks < 4; ++ks) {
      __syncthreads();
      // stage B chunk: Bt[kc][n] = codebook[nc*64+n][ks*32+kc]
      {
        const int nl = tid >> 2;
        const int fi0 = tid & 3;
        const float* rp = cbbase + (size_t)(nc * 64 + nl) * 128 + ks * 32;
#pragma unroll
        for (int h = 0; h < 2; ++h) {
          const int fi = fi0 + h * 4;
          float4 v = *(const float4*)(rp + fi * 4);
          Bt[(fi * 4 + 0) * 64 + nl] = v.x;
          Bt[(fi * 4 + 1) * 64 + nl] = v.y;
          Bt[(fi * 4 + 2) * 64 + nl] = v.z;
          Bt[(fi * 4 + 3) * 64 + nl] = v.w;
        }
      }
      __syncthreads();
#pragma unroll
      for (int kc = 0; kc < 32; ++kc) {
        float4 a = *(const float4*)&At[(ks * 32 + kc) * 64 + tm * 4];
        float4 bv = *(const float4*)&Bt[kc * 64 + tn * 4];
        float av[4] = {a.x, a.y, a.z, a.w};
        float bb[4] = {bv.x, bv.y, bv.z, bv.w};
#pragma unroll
        for (int r = 0; r < 4; ++r)
#pragma unroll
          for (int c = 0; c < 4; ++c) acc[r][c] = fmaf(av[r], bb[c], acc[r][c]);
      }
    }
    // fused distance + argmin update (cols ascending per thread -> first-min kept)
#pragma unroll
    for (int r = 0; r < 4; ++r) {
      const float x2v = x2s[tm * 4 + r];
#pragma unroll
      for (int c = 0; c < 4; ++c) {
        const int n = nc * 64 + tn * 4 + c;
        const float d2 = x2v - 2.0f * acc[r][c] + c2b[n];
        if (d2 < best[r]) { best[r] = d2; bidx[r] = n; }
      }
    }
  }

#pragma unroll
  for (int r = 0; r < 4; ++r) {
    redD[(tm * 4 + r) * 16 + tn] = best[r];
    redI[(tm * 4 + r) * 16 + tn] = bidx[r];
  }
  __syncthreads();
  if (tid < 64) {
    float bd = redD[tid * 16];
    int bi = redI[tid * 16];
#pragma unroll
    for (int j = 1; j < 16; ++j) {
      float d = redD[tid * 16 + j];
      int i2 = redI[tid * 16 + j];
      if (d < bd || (d == bd && i2 < bi)) { bd = d; bi = i2; }
    }
    const int m = m0 + tid;
    if (m < MROWS) {
      const int b = m / TFR;
      const int t = m - b * TFR;
      out[((size_t)b * 4 + cb) * TFR + t] = bi;
    }
  }
}

// ---------------- launch ----------------
extern "C" void kernel_launch(void* const* d_in, const int* in_sizes, int n_in,
                              void* d_out, int out_size, void* d_ws, size_t ws_size,
                              hipStream_t stream) {
  if (ws_size < WS_NEEDED) return;  // fail visibly (out stays poisoned)

  const float* wav = (const float*)d_in[0];
  const float* w1 = (const float*)d_in[1];
  const float* b1 = (const float*)d_in[2];
  const float* w2 = (const float*)d_in[3];
  const float* b2 = (const float*)d_in[4];
  const float* cbs = (const float*)d_in[5];
  int* out = (int*)d_out;

  char* W = (char*)d_ws;
  float* win = (float*)(W + OFF_WIN);
  float2* tw = (float2*)(W + OFF_TW);
  float2* utw = (float2*)(W + OFF_UTW);
  float* FB = (float*)(W + OFF_FB);
  float* wb1 = (float*)(W + OFF_WB1);
  float* wb2 = (float*)(W + OFF_WB2);
  float* c2 = (float*)(W + OFF_C2);
  float* lm = (float*)(W + OFF_LM);
  float* h = (float*)(W + OFF_H);
  float* fe = (float*)(W + OFF_FE);

  k_setup_tab<<<1, 1024, 0, stream>>>(win, tw, utw);
  k_setup_fb<<<513, 128, 0, stream>>>(FB);
  k_wt<<<(256 * 128 * 3 + 255) / 256, 256, 0, stream>>>(w1, wb1, 256, 128);
  k_wt<<<(512 * 256 * 3 + 255) / 256, 256, 0, stream>>>(w2, wb2, 512, 256);
  k_c2<<<16, 256, 0, stream>>>(cbs, c2);

  k_logmel<<<MROWS, 256, 0, stream>>>(wav, win, tw, utw, FB, lm);
  k_conv<128, 256, true><<<dim3(188, 4), 256, 0, stream>>>(lm, wb1, b1, h);
  k_conv<256, 512, false><<<dim3(188, 8), 256, 0, stream>>>(h, wb2, b2, fe);
  k_vq<<<dim3(188, 4), 256, 0, stream>>>(fe, cbs, c2, out);
}

// Round 2
// 468.406 us; speedup vs baseline: 1.3169x; 1.3169x over previous
//
#include <hip/hip_runtime.h>
#include <hip/hip_bf16.h>
#include <float.h>

#define PI_D 3.14159265358979323846

// ---------------- problem constants ----------------
#define LWAV 240000
#define TFR  751            // frames per batch
#define BATCH 16
#define MROWS (BATCH * TFR) // 12016
#define NMEL 128
#define PITCH 12032         // padded M for transposed feature rows (>= 12032 = 188*64)
#define MAXW 40             // max nonzero bins per mel triangle (actual max ~25)

// ---------------- workspace layout (bytes) ----------------
#define OFF_WIN    0u            // 1024 f32
#define OFF_TW512  4096u         // 512 float2
#define OFF_UTW    8192u         // 513 float2 (4104 B)
#define OFF_MELW   12304u        // 128*40 f32
#define OFF_MELSL  32784u        // 128 int2
#define OFF_WB1    33808u        // 384*256 f32
#define OFF_WB2    427024u       // 768*512 f32
#define OFF_C2     1999888u      // 4*1024 f32
#define OFF_CBT    2016272u      // 4*128*1024 f32 (codebooks transposed)
#define OFF_H      4113424u      // 12016*256 f32
#define OFF_LM     16417808u     // 12016*128 f32
#define OFF_FET    16417808u     // 512*12032 f32 (overlays lm; lm dead before conv2)
#define WS_NEEDED  41059344u

#define WAVE_LDS_FENCE() asm volatile("s_waitcnt lgkmcnt(0)" ::: "memory")

// ---------------- setup kernels ----------------
__global__ void k_setup_tab(float* __restrict__ win, float2* __restrict__ tw512,
                            float2* __restrict__ utw) {
  int t = threadIdx.x;  // 1024 threads
  if (t < 1024) {
    double v = 0.5 * (1.0 - cos(2.0 * PI_D * (double)t / 1024.0));
    win[t] = (float)v;
  }
  if (t < 512) {
    double a = -2.0 * PI_D * (double)t / 512.0;
    tw512[t] = make_float2((float)cos(a), (float)sin(a));
  }
  if (t < 513) {
    double a = -2.0 * PI_D * (double)t / 1024.0;
    utw[t] = make_float2((float)cos(a), (float)sin(a));
  }
}

__device__ __forceinline__ double fpt_d(int j) {
  double melmax = 2595.0 * log10(1.0 + 12000.0 / 700.0);
  double mp = melmax * (double)j / 129.0;
  return 700.0 * (pow(10.0, mp / 2595.0) - 1.0);
}

// compact sparse mel filterbank: per mel, start bin + weights
__global__ void k_melw(float* __restrict__ melw, int2* __restrict__ melsl) {
  int m = threadIdx.x;  // 128
  double f0 = fpt_d(m), f1 = fpt_d(m + 1), f2 = fpt_d(m + 2);
  const double binw = 12000.0 / 512.0;
  int s = (int)floor(f0 / binw) + 1;
  if (s < 0) s = 0;
  int e = (int)ceil(f2 / binw) - 1;
  if (e > 512) e = 512;
  int len = e - s + 1;
  if (len < 0) len = 0;
  if (len > MAXW) len = MAXW;
  melsl[m] = make_int2(s, len);
  for (int j = 0; j < MAXW; ++j) {
    double freq = binw * (double)(s + j);
    double down = (freq - f0) / (f1 - f0);
    double up = (f2 - freq) / (f2 - f1);
    double v = fmin(down, up);
    v = fmax(0.0, v);
    melw[m * MAXW + j] = (j < len) ? (float)v : 0.f;
  }
}

// wt[(dt*C+i)*O + o] = w[(o*C+i)*3 + dt]
__global__ void k_wt(const float* __restrict__ w, float* __restrict__ wt,
                     int O, int C) {
  int idx = blockIdx.x * 256 + threadIdx.x;
  int total = O * C * 3;
  if (idx >= total) return;
  int o = idx % O;
  int rest = idx / O;
  int i = rest % C;
  int dt = rest / C;
  wt[(dt * C + i) * O + o] = w[(o * C + i) * 3 + dt];
}

__global__ void k_c2(const float* __restrict__ cb, float* __restrict__ c2) {
  int v = blockIdx.x * 256 + threadIdx.x;  // 4096 rows
  if (v >= 4096) return;
  const float* r = cb + (size_t)v * 128;
  float s = 0.f;
#pragma unroll 8
  for (int i = 0; i < 128; ++i) s = fmaf(r[i], r[i], s);
  c2[v] = s;
}

// cbT[(cb*128 + d)*1024 + v] = cbs[(cb*1024 + v)*128 + d]
__global__ void k_cbt(const float* __restrict__ cb, float* __restrict__ cbT) {
  int idx = blockIdx.x * 256 + threadIdx.x;  // 524288 total
  int v = idx & 1023;
  int d = (idx >> 10) & 127;
  int c = idx >> 17;
  cbT[idx] = cb[(size_t)((c << 10) + v) * 128 + d];
}

// ---------------- complex helpers / radix-8 DFT ----------------
__device__ __forceinline__ float2 cadd(float2 a, float2 b) { return make_float2(a.x + b.x, a.y + b.y); }
__device__ __forceinline__ float2 csub(float2 a, float2 b) { return make_float2(a.x - b.x, a.y - b.y); }
__device__ __forceinline__ float2 cmul(float2 a, float2 b) {
  return make_float2(a.x * b.x - a.y * b.y, a.x * b.y + a.y * b.x);
}
__device__ __forceinline__ float2 mulnegi(float2 a) { return make_float2(a.y, -a.x); }  // a * (-i)

// o[p] = sum_j d[j] * W8^{j p},  W8 = e^{-i pi/4}
__device__ __forceinline__ void dft8(const float2* d, float2* o) {
  const float S = 0.70710678118654752440f;
  float2 f0 = cadd(d[0], d[4]), f1 = csub(d[0], d[4]);
  float2 f2 = cadd(d[2], d[6]), f3 = csub(d[2], d[6]);
  float2 h0 = cadd(d[1], d[5]), h1 = csub(d[1], d[5]);
  float2 h2 = cadd(d[3], d[7]), h3 = csub(d[3], d[7]);
  float2 E0 = cadd(f0, f2), E2 = csub(f0, f2);
  float2 nif3 = mulnegi(f3);
  float2 E1 = cadd(f1, nif3), E3 = csub(f1, nif3);
  float2 O0 = cadd(h0, h2), O2 = csub(h0, h2);
  float2 nih3 = mulnegi(h3);
  float2 O1 = cadd(h1, nih3), O3 = csub(h1, nih3);
  float2 w1o = make_float2(S * (O1.x + O1.y), S * (O1.y - O1.x));   // O1 * W8^1
  float2 w2o = mulnegi(O2);                                          // O2 * W8^2
  float2 w3o = make_float2(S * (O3.y - O3.x), -S * (O3.x + O3.y));   // O3 * W8^3
  o[0] = cadd(E0, O0);  o[4] = csub(E0, O0);
  o[1] = cadd(E1, w1o); o[5] = csub(E1, w1o);
  o[2] = cadd(E2, w2o); o[6] = csub(E2, w2o);
  o[3] = cadd(E3, w3o); o[7] = csub(E3, w3o);
}

__device__ __forceinline__ float powspec(const float2* Z, const float2* __restrict__ utw,
                                         int k) {
  float2 Zk = Z[k & 511];
  float2 Zm = Z[(512 - k) & 511];
  float2 ut = utw[k];
  float fer = 0.5f * (Zk.x + Zm.x);
  float fei = 0.5f * (Zk.y - Zm.y);
  float fo_r = 0.5f * (Zk.y + Zm.y);
  float fo_i = -0.5f * (Zk.x - Zm.x);
  float xr = fer + ut.x * fo_r - ut.y * fo_i;
  float xi = fei + ut.x * fo_i + ut.y * fo_r;
  return xr * xr + xi * xi;
}

// ---------------- log-mel: one wave per frame, register radix-8 FFT ----------------
__global__ __launch_bounds__(256) void k_logmel2(
    const float* __restrict__ wav, const float* __restrict__ win,
    const float2* __restrict__ tw512, const float2* __restrict__ utw,
    const float* __restrict__ melw, const int2* __restrict__ melsl,
    float* __restrict__ lm) {
  __shared__ float2 zbuf[4][512];
  __shared__ float pbuf[4][516];

  const int w = threadIdx.x >> 6;
  const int t = threadIdx.x & 63;
  const int fr = blockIdx.x * 4 + w;  // grid 3004 * 4 = 12016 exact
  const int b = fr / TFR;
  const int tt = fr - b * TFR;
  const float* wv = wav + (size_t)b * LWAV;
  float2* Z = zbuf[w];
  float* p = pbuf[w];

  const int base = tt * 320 - 512;

  // load 1024 samples (pairs -> complex), window
  float2 c[8];
  if (base >= 0 && base + 1024 <= LWAV) {
    const float2* wv2 = (const float2*)(wv + base);
    const float2* wn2 = (const float2*)win;
#pragma unroll
    for (int j = 0; j < 8; ++j) {
      int mm = t + 64 * j;
      float2 xv = wv2[mm];
      float2 wn = wn2[mm];
      c[j] = make_float2(xv.x * wn.x, xv.y * wn.y);
    }
  } else {
#pragma unroll
    for (int j = 0; j < 8; ++j) {
      int mm = t + 64 * j;
      int n0 = base + 2 * mm, n1 = n0 + 1;
      int j0 = n0 < 0 ? -n0 : (n0 >= LWAV ? 2 * LWAV - 2 - n0 : n0);
      int j1 = n1 < 0 ? -n1 : (n1 >= LWAV ? 2 * LWAV - 2 - n1 : n1);
      c[j] = make_float2(wv[j0] * win[2 * mm], wv[j1] * win[2 * mm + 1]);
    }
  }

  // ---- pass 1: radix-8 over j (n = m + 64 j, m = lane t) ----
  float2 e[8];
  dft8(c, e);
#pragma unroll
  for (int pp = 1; pp < 8; ++pp) e[pp] = cmul(e[pp], tw512[(t * pp) & 511]);
  // transpose 1 (XOR swizzle, 2-way max)
#pragma unroll
  for (int pp = 0; pp < 8; ++pp) Z[pp * 64 + (t ^ (pp << 3))] = e[pp];
  WAVE_LDS_FENCE();

  const int P = t >> 3, M = t & 7;
  float2 g[8];
#pragma unroll
  for (int v = 0; v < 8; ++v) g[v] = Z[P * 64 + ((M + 8 * v) ^ (P << 3))];
  WAVE_LDS_FENCE();

  // ---- pass 2: z_P over m64 = M + 8v ----
  float2 y[8];
  dft8(g, y);
#pragma unroll
  for (int aa = 1; aa < 8; ++aa) y[aa] = cmul(y[aa], tw512[(8 * M * aa) & 511]);  // W64^{M a}
  // transpose 2
#pragma unroll
  for (int aa = 0; aa < 8; ++aa) Z[aa * 64 + (((M << 3) + P) ^ (aa << 3))] = y[aa];
  WAVE_LDS_FENCE();

  float2 yv[8];
#pragma unroll
  for (int u = 0; u < 8; ++u) yv[u] = Z[P * 64 + (((u << 3) + M) ^ (P << 3))];
  WAVE_LDS_FENCE();

  // ---- pass 3: 8-pt DFT over u; X[64b + 8*(t>>3) + (t&7)] = out[b] = X[64b + t]
  float2 X[8];
  dft8(yv, X);
#pragma unroll
  for (int bb = 0; bb < 8; ++bb) Z[bb * 64 + t] = X[bb];
  WAVE_LDS_FENCE();

  // ---- power spectrum (real-FFT unpack), 513 bins ----
#pragma unroll
  for (int j = 0; j < 8; ++j) {
    int k = t + 64 * j;
    p[k] = powspec(Z, utw, k);
  }
  if (t == 0) p[512] = powspec(Z, utw, 512);
  WAVE_LDS_FENCE();

  // ---- sparse mel projection + log: 2 mels per lane ----
  float mv[2];
#pragma unroll
  for (int h = 0; h < 2; ++h) {
    int m = 2 * t + h;
    int2 sl = melsl[m];
    float acc = 0.f;
    const float* wrow = melw + m * MAXW;
    for (int j = 0; j < sl.y; ++j) acc = fmaf(p[sl.x + j], wrow[j], acc);
    mv[h] = logf(fmaxf(acc, 1e-5f));
  }
  ((float2*)(lm + (size_t)fr * NMEL))[t] = make_float2(mv[0], mv[1]);
}

// ---------------- conv-as-GEMM kernel ----------------
// out[m][n] = act( bias[n] + sum_k A[m][k] * wt[k][n] ),  k = dt*C + i,
// A[m][k] = in[(m + dt - 1)][i] with per-batch zero padding at t edges.
// TRANSOUT: write out[n][m] with row pitch PITCH (for VQ consumption).
template <int C, int N, bool GELU, bool TRANSOUT>
__global__ __launch_bounds__(256) void k_conv(const float* __restrict__ in,
                                              const float* __restrict__ wt,
                                              const float* __restrict__ bias,
                                              float* __restrict__ out) {
  constexpr int K = 3 * C;
  __shared__ float At[32 * 64];  // [kc][m]
  __shared__ float Bt[32 * 64];  // [kc][n]
  const int m0 = blockIdx.x * 64;
  const int n0 = blockIdx.y * 64;
  const int tid = threadIdx.x;
  const int tm = tid >> 4, tn = tid & 15;

  float acc[4][4] = {};

  const int ml = tid >> 2;          // staging row 0..63
  const int fi0 = tid & 3;
  const int mload = m0 + ml;
  const int bql = mload / TFR;
  const int tql = mload - bql * TFR;

  for (int k0 = 0; k0 < K; k0 += 32) {
    const int dt = k0 / C;
    const int i0 = k0 - dt * C;
    // stage A (transposed)
    {
      const int ttq = tql + dt - 1;
      const bool ok = (mload < MROWS) && (ttq >= 0) && (ttq < TFR);
      const float* rp = in + (size_t)(mload + dt - 1) * C + i0;
#pragma unroll
      for (int h = 0; h < 2; ++h) {
        const int fi = fi0 + h * 4;
        float4 v = ok ? *(const float4*)(rp + fi * 4) : make_float4(0.f, 0.f, 0.f, 0.f);
        At[(fi * 4 + 0) * 64 + ml] = v.x;
        At[(fi * 4 + 1) * 64 + ml] = v.y;
        At[(fi * 4 + 2) * 64 + ml] = v.z;
        At[(fi * 4 + 3) * 64 + ml] = v.w;
      }
    }
    // stage B
    {
#pragma unroll
      for (int h = 0; h < 2; ++h) {
        const int e = tid + h * 256;  // float4 id 0..511
        const int kc = e >> 4;
        const int nf = e & 15;
        float4 v = *(const float4*)(wt + (size_t)(k0 + kc) * N + n0 + nf * 4);
        *(float4*)&Bt[kc * 64 + nf * 4] = v;
      }
    }
    __syncthreads();
#pragma unroll
    for (int kc = 0; kc < 32; ++kc) {
      float4 a = *(const float4*)&At[kc * 64 + tm * 4];
      float4 bv = *(const float4*)&Bt[kc * 64 + tn * 4];
      float av[4] = {a.x, a.y, a.z, a.w};
      float bb[4] = {bv.x, bv.y, bv.z, bv.w};
#pragma unroll
      for (int r = 0; r < 4; ++r)
#pragma unroll
        for (int cq = 0; cq < 4; ++cq) acc[r][cq] = fmaf(av[r], bb[cq], acc[r][cq]);
    }
    __syncthreads();
  }

  if (TRANSOUT) {
#pragma unroll
    for (int cq = 0; cq < 4; ++cq) {
      const int n = n0 + tn * 4 + cq;
      const float bv = bias[n];
      float4 o = make_float4(acc[0][cq] + bv, acc[1][cq] + bv,
                             acc[2][cq] + bv, acc[3][cq] + bv);
      *(float4*)(out + (size_t)n * PITCH + m0 + tm * 4) = o;
    }
  } else {
#pragma unroll
    for (int r = 0; r < 4; ++r) {
      const int m = m0 + tm * 4 + r;
      if (m >= MROWS) continue;
      float4 o;
      float* ov = (float*)&o;
#pragma unroll
      for (int cq = 0; cq < 4; ++cq) {
        float v = acc[r][cq] + bias[n0 + tn * 4 + cq];
        if (GELU) v = 0.5f * v * (1.0f + erff(v * 0.7071067811865476f));
        ov[cq] = v;
      }
      *(float4*)(out + (size_t)m * N + n0 + tn * 4) = o;
    }
  }
}

// ---------------- VQ kernel v2: A in LDS [k][m], B streamed from L2 ----------------
#define VQ_LOADB(dst, kcbase)                                          \
  _Pragma("unroll")                                                    \
  for (int ii = 0; ii < 8; ++ii)                                       \
    dst[ii] = *(const float4*)(Bn + (size_t)((kcbase) + ii) * 1024);

#define VQ_COMP(buf, kcbase)                                           \
  _Pragma("unroll")                                                    \
  for (int ii = 0; ii < 8; ++ii) {                                     \
    float4 a4 = *(const float4*)(Ap + (size_t)((kcbase) + ii) * 64);   \
    float av[4] = {a4.x, a4.y, a4.z, a4.w};                            \
    const float* bv = (const float*)&buf[ii];                          \
    _Pragma("unroll")                                                  \
    for (int r = 0; r < 4; ++r)                                        \
      _Pragma("unroll")                                                \
      for (int cq = 0; cq < 4; ++cq)                                   \
        acc[r][cq] = fmaf(av[r], bv[cq], acc[r][cq]);                  \
  }

__global__ __launch_bounds__(256) void k_vq2(const float* __restrict__ feT,
                                             const float* __restrict__ cbT,
                                             const float* __restrict__ c2,
                                             int* __restrict__ out) {
  __shared__ float At[128 * 64];  // [k][m] linear
  __shared__ float x2s[64];

  const int m0 = blockIdx.x * 64;
  const int cb = blockIdx.y;
  const int tid = threadIdx.x;
  const int tm = tid >> 4, tn = tid & 15;

  // stage A tile: feT rows cb*128..+127, cols m0..m0+63 — linear, conflict-free
  {
    const float* gbase = feT + (size_t)(cb * 128) * PITCH + m0;
#pragma unroll
    for (int h = 0; h < 8; ++h) {
      int id = h * 256 + tid;          // float4 id 0..2047
      int row = id >> 4, col = id & 15;
      float4 v = *(const float4*)(gbase + (size_t)row * PITCH + col * 4);
      *(float4*)&At[id * 4] = v;
    }
  }
  __syncthreads();
  if (tid < 64) {
    float s = 0.f;
#pragma unroll 8
    for (int kc = 0; kc < 128; ++kc) {
      float a = At[kc * 64 + tid];
      s = fmaf(a, a, s);
    }
    x2s[tid] = s;
  }
  __syncthreads();

  float best[4] = {FLT_MAX, FLT_MAX, FLT_MAX, FLT_MAX};
  int bidx[4] = {0, 0, 0, 0};
  const float* Bp = cbT + (size_t)cb * (128 * 1024) + tn * 4;
  const float* c2b = c2 + cb * 1024;
  const float* Ap = At + tm * 4;

  for (int nc = 0; nc < 16; ++nc) {
    const float* Bn = Bp + nc * 64;
    float4 bA[8], bB[8];
    float acc[4][4] = {};
    VQ_LOADB(bA, 0);
    for (int kc0 = 0; kc0 < 112; kc0 += 16) {
      VQ_LOADB(bB, kc0 + 8);
      VQ_COMP(bA, kc0);
      VQ_LOADB(bA, kc0 + 16);
      VQ_COMP(bB, kc0 + 8);
    }
    VQ_LOADB(bB, 120);
    VQ_COMP(bA, 112);
    VQ_COMP(bB, 120);

    // fused distance + argmin (cols ascending per thread -> first-min kept)
    float4 c24 = *(const float4*)(c2b + nc * 64 + tn * 4);
    const float cc[4] = {c24.x, c24.y, c24.z, c24.w};
#pragma unroll
    for (int r = 0; r < 4; ++r) {
      const float x2v = x2s[tm * 4 + r];
#pragma unroll
      for (int cq = 0; cq < 4; ++cq) {
        const int n = nc * 64 + tn * 4 + cq;
        const float d2 = x2v - 2.0f * acc[r][cq] + cc[cq];
        if (d2 < best[r]) { best[r] = d2; bidx[r] = n; }
      }
    }
  }

  // reduction (overlay dead At: redD = first 4KB, redI = next 4KB)
  __syncthreads();
  float* redD = At;
  int* redI = (int*)(At + 1024);
#pragma unroll
  for (int r = 0; r < 4; ++r) {
    redD[(tm * 4 + r) * 16 + tn] = best[r];
    redI[(tm * 4 + r) * 16 + tn] = bidx[r];
  }
  __syncthreads();
  if (tid < 64) {
    float bd = redD[tid * 16];
    int bi = redI[tid * 16];
#pragma unroll
    for (int j = 1; j < 16; ++j) {
      float d = redD[tid * 16 + j];
      int i2 = redI[tid * 16 + j];
      if (d < bd || (d == bd && i2 < bi)) { bd = d; bi = i2; }
    }
    const int m = m0 + tid;
    if (m < MROWS) {
      const int b = m / TFR;
      const int t = m - b * TFR;
      out[((size_t)b * 4 + cb) * TFR + t] = bi;
    }
  }
}

// ---------------- launch ----------------
extern "C" void kernel_launch(void* const* d_in, const int* in_sizes, int n_in,
                              void* d_out, int out_size, void* d_ws, size_t ws_size,
                              hipStream_t stream) {
  if (ws_size < WS_NEEDED) return;  // fail visibly (out stays poisoned)

  const float* wav = (const float*)d_in[0];
  const float* w1 = (const float*)d_in[1];
  const float* b1 = (const float*)d_in[2];
  const float* w2 = (const float*)d_in[3];
  const float* b2 = (const float*)d_in[4];
  const float* cbs = (const float*)d_in[5];
  int* out = (int*)d_out;

  char* W = (char*)d_ws;
  float* win = (float*)(W + OFF_WIN);
  float2* tw512 = (float2*)(W + OFF_TW512);
  float2* utw = (float2*)(W + OFF_UTW);
  float* melw = (float*)(W + OFF_MELW);
  int2* melsl = (int2*)(W + OFF_MELSL);
  float* wb1 = (float*)(W + OFF_WB1);
  float* wb2 = (float*)(W + OFF_WB2);
  float* c2 = (float*)(W + OFF_C2);
  float* cbT = (float*)(W + OFF_CBT);
  float* h = (float*)(W + OFF_H);
  float* lm = (float*)(W + OFF_LM);
  float* feT = (float*)(W + OFF_FET);

  k_setup_tab<<<1, 1024, 0, stream>>>(win, tw512, utw);
  k_melw<<<1, 128, 0, stream>>>(melw, melsl);
  k_wt<<<(256 * 128 * 3 + 255) / 256, 256, 0, stream>>>(w1, wb1, 256, 128);
  k_wt<<<(512 * 256 * 3 + 255) / 256, 256, 0, stream>>>(w2, wb2, 512, 256);
  k_c2<<<16, 256, 0, stream>>>(cbs, c2);
  k_cbt<<<2048, 256, 0, stream>>>(cbs, cbT);

  k_logmel2<<<3004, 256, 0, stream>>>(wav, win, tw512, utw, melw, melsl, lm);
  k_conv<128, 256, true, false><<<dim3(188, 4), 256, 0, stream>>>(lm, wb1, b1, h);
  k_conv<256, 512, false, true><<<dim3(188, 8), 256, 0, stream>>>(h, wb2, b2, feT);
  k_vq2<<<dim3(188, 4), 256, 0, stream>>>(feT, cbT, c2, out);
}

// Round 3
// 438.694 us; speedup vs baseline: 1.4061x; 1.0677x over previous
//
#include <hip/hip_runtime.h>
#include <hip/hip_bf16.h>
#include <float.h>

#define PI_D 3.14159265358979323846

// ---------------- problem constants ----------------
#define LWAV 240000
#define TFR  751            // frames per batch
#define BATCH 16
#define MROWS (BATCH * TFR) // 12016
#define NMEL 128
#define PITCH 12032         // padded M for transposed feature rows (188*64)
#define MAXW 40             // max nonzero bins per mel triangle (actual max ~25)

// ---------------- workspace layout (bytes) ----------------
#define OFF_WIN    0u            // 1024 f32
#define OFF_TW512  4096u         // 512 float2
#define OFF_UTW    8192u         // 513 float2 (4104 B)
#define OFF_MELW   12304u        // 128*40 f32
#define OFF_MELSL  32784u        // 128 int2
#define OFF_WB1    33808u        // 384*256 f32
#define OFF_WB2    427024u       // 768*512 f32
#define OFF_C2     1999888u      // 4*1024 f32
#define OFF_CBT    2016272u      // 4*128*1024 f32 (codebooks transposed)
#define OFF_H      4113424u      // 12016*256 f32
#define OFF_PB     4113424u      // 4*16*12032 float2 (6.16MB, overlays h; h dead before VQ)
#define OFF_LM     16417808u     // 12016*128 f32
#define OFF_FET    16417808u     // 512*12032 f32 (overlays lm; lm dead before conv2)
#define WS_NEEDED  41059344u

#define WAVE_LDS_FENCE() asm volatile("s_waitcnt lgkmcnt(0)" ::: "memory")

// ---------------- setup kernels ----------------
__global__ void k_setup_tab(float* __restrict__ win, float2* __restrict__ tw512,
                            float2* __restrict__ utw) {
  int t = threadIdx.x;  // 1024 threads
  if (t < 1024) {
    double v = 0.5 * (1.0 - cos(2.0 * PI_D * (double)t / 1024.0));
    win[t] = (float)v;
  }
  if (t < 512) {
    double a = -2.0 * PI_D * (double)t / 512.0;
    tw512[t] = make_float2((float)cos(a), (float)sin(a));
  }
  if (t < 513) {
    double a = -2.0 * PI_D * (double)t / 1024.0;
    utw[t] = make_float2((float)cos(a), (float)sin(a));
  }
}

__device__ __forceinline__ double fpt_d(int j) {
  double melmax = 2595.0 * log10(1.0 + 12000.0 / 700.0);
  double mp = melmax * (double)j / 129.0;
  return 700.0 * (pow(10.0, mp / 2595.0) - 1.0);
}

// compact sparse mel filterbank: per mel, start bin + weights
__global__ void k_melw(float* __restrict__ melw, int2* __restrict__ melsl) {
  int m = threadIdx.x;  // 128
  double f0 = fpt_d(m), f1 = fpt_d(m + 1), f2 = fpt_d(m + 2);
  const double binw = 12000.0 / 512.0;
  int s = (int)floor(f0 / binw) + 1;
  if (s < 0) s = 0;
  int e = (int)ceil(f2 / binw) - 1;
  if (e > 512) e = 512;
  int len = e - s + 1;
  if (len < 0) len = 0;
  if (len > MAXW) len = MAXW;
  melsl[m] = make_int2(s, len);
  for (int j = 0; j < MAXW; ++j) {
    double freq = binw * (double)(s + j);
    double down = (freq - f0) / (f1 - f0);
    double up = (f2 - freq) / (f2 - f1);
    double v = fmin(down, up);
    v = fmax(0.0, v);
    melw[m * MAXW + j] = (j < len) ? (float)v : 0.f;
  }
}

// wt[(dt*C+i)*O + o] = w[(o*C+i)*3 + dt]
__global__ void k_wt(const float* __restrict__ w, float* __restrict__ wt,
                     int O, int C) {
  int idx = blockIdx.x * 256 + threadIdx.x;
  int total = O * C * 3;
  if (idx >= total) return;
  int o = idx % O;
  int rest = idx / O;
  int i = rest % C;
  int dt = rest / C;
  wt[(dt * C + i) * O + o] = w[(o * C + i) * 3 + dt];
}

__global__ void k_c2(const float* __restrict__ cb, float* __restrict__ c2) {
  int v = blockIdx.x * 256 + threadIdx.x;  // 4096 rows
  if (v >= 4096) return;
  const float* r = cb + (size_t)v * 128;
  float s = 0.f;
#pragma unroll 8
  for (int i = 0; i < 128; ++i) s = fmaf(r[i], r[i], s);
  c2[v] = s;
}

// cbT[(cb*128 + d)*1024 + v] = cbs[(cb*1024 + v)*128 + d]
__global__ void k_cbt(const float* __restrict__ cb, float* __restrict__ cbT) {
  int idx = blockIdx.x * 256 + threadIdx.x;  // 524288 total
  int v = idx & 1023;
  int d = (idx >> 10) & 127;
  int c = idx >> 17;
  cbT[idx] = cb[(size_t)((c << 10) + v) * 128 + d];
}

// ---------------- complex helpers / radix-8 DFT ----------------
__device__ __forceinline__ float2 cadd(float2 a, float2 b) { return make_float2(a.x + b.x, a.y + b.y); }
__device__ __forceinline__ float2 csub(float2 a, float2 b) { return make_float2(a.x - b.x, a.y - b.y); }
__device__ __forceinline__ float2 cmul(float2 a, float2 b) {
  return make_float2(a.x * b.x - a.y * b.y, a.x * b.y + a.y * b.x);
}
__device__ __forceinline__ float2 mulnegi(float2 a) { return make_float2(a.y, -a.x); }  // a * (-i)

// o[p] = sum_j d[j] * W8^{j p},  W8 = e^{-i pi/4}
__device__ __forceinline__ void dft8(const float2* d, float2* o) {
  const float S = 0.70710678118654752440f;
  float2 f0 = cadd(d[0], d[4]), f1 = csub(d[0], d[4]);
  float2 f2 = cadd(d[2], d[6]), f3 = csub(d[2], d[6]);
  float2 h0 = cadd(d[1], d[5]), h1 = csub(d[1], d[5]);
  float2 h2 = cadd(d[3], d[7]), h3 = csub(d[3], d[7]);
  float2 E0 = cadd(f0, f2), E2 = csub(f0, f2);
  float2 nif3 = mulnegi(f3);
  float2 E1 = cadd(f1, nif3), E3 = csub(f1, nif3);
  float2 O0 = cadd(h0, h2), O2 = csub(h0, h2);
  float2 nih3 = mulnegi(h3);
  float2 O1 = cadd(h1, nih3), O3 = csub(h1, nih3);
  float2 w1o = make_float2(S * (O1.x + O1.y), S * (O1.y - O1.x));   // O1 * W8^1
  float2 w2o = mulnegi(O2);                                          // O2 * W8^2
  float2 w3o = make_float2(S * (O3.y - O3.x), -S * (O3.x + O3.y));   // O3 * W8^3
  o[0] = cadd(E0, O0);  o[4] = csub(E0, O0);
  o[1] = cadd(E1, w1o); o[5] = csub(E1, w1o);
  o[2] = cadd(E2, w2o); o[6] = csub(E2, w2o);
  o[3] = cadd(E3, w3o); o[7] = csub(E3, w3o);
}

__device__ __forceinline__ float powspec(const float2* Z, const float2* __restrict__ utw,
                                         int k) {
  float2 Zk = Z[k & 511];
  float2 Zm = Z[(512 - k) & 511];
  float2 ut = utw[k];
  float fer = 0.5f * (Zk.x + Zm.x);
  float fei = 0.5f * (Zk.y - Zm.y);
  float fo_r = 0.5f * (Zk.y + Zm.y);
  float fo_i = -0.5f * (Zk.x - Zm.x);
  float xr = fer + ut.x * fo_r - ut.y * fo_i;
  float xi = fei + ut.x * fo_i + ut.y * fo_r;
  return xr * xr + xi * xi;
}

// ---------------- log-mel: one wave per frame, register radix-8 FFT ----------------
__global__ __launch_bounds__(256) void k_logmel2(
    const float* __restrict__ wav, const float* __restrict__ win,
    const float2* __restrict__ tw512, const float2* __restrict__ utw,
    const float* __restrict__ melw, const int2* __restrict__ melsl,
    float* __restrict__ lm) {
  __shared__ float2 zbuf[4][512];
  __shared__ float pbuf[4][516];

  const int w = threadIdx.x >> 6;
  const int t = threadIdx.x & 63;
  const int fr = blockIdx.x * 4 + w;  // grid 3004 * 4 = 12016 exact
  const int b = fr / TFR;
  const int tt = fr - b * TFR;
  const float* wv = wav + (size_t)b * LWAV;
  float2* Z = zbuf[w];
  float* p = pbuf[w];

  const int base = tt * 320 - 512;

  // load 1024 samples (pairs -> complex), window
  float2 c[8];
  if (base >= 0 && base + 1024 <= LWAV) {
    const float2* wv2 = (const float2*)(wv + base);
    const float2* wn2 = (const float2*)win;
#pragma unroll
    for (int j = 0; j < 8; ++j) {
      int mm = t + 64 * j;
      float2 xv = wv2[mm];
      float2 wn = wn2[mm];
      c[j] = make_float2(xv.x * wn.x, xv.y * wn.y);
    }
  } else {
#pragma unroll
    for (int j = 0; j < 8; ++j) {
      int mm = t + 64 * j;
      int n0 = base + 2 * mm, n1 = n0 + 1;
      int j0 = n0 < 0 ? -n0 : (n0 >= LWAV ? 2 * LWAV - 2 - n0 : n0);
      int j1 = n1 < 0 ? -n1 : (n1 >= LWAV ? 2 * LWAV - 2 - n1 : n1);
      c[j] = make_float2(wv[j0] * win[2 * mm], wv[j1] * win[2 * mm + 1]);
    }
  }

  // ---- pass 1: radix-8 over j (n = m + 64 j, m = lane t) ----
  float2 e[8];
  dft8(c, e);
#pragma unroll
  for (int pp = 1; pp < 8; ++pp) e[pp] = cmul(e[pp], tw512[(t * pp) & 511]);
  // transpose 1 (XOR swizzle, 2-way max)
#pragma unroll
  for (int pp = 0; pp < 8; ++pp) Z[pp * 64 + (t ^ (pp << 3))] = e[pp];
  WAVE_LDS_FENCE();

  const int P = t >> 3, M = t & 7;
  float2 g[8];
#pragma unroll
  for (int v = 0; v < 8; ++v) g[v] = Z[P * 64 + ((M + 8 * v) ^ (P << 3))];
  WAVE_LDS_FENCE();

  // ---- pass 2: z_P over m64 = M + 8v ----
  float2 y[8];
  dft8(g, y);
#pragma unroll
  for (int aa = 1; aa < 8; ++aa) y[aa] = cmul(y[aa], tw512[(8 * M * aa) & 511]);  // W64^{M a}
  // transpose 2
#pragma unroll
  for (int aa = 0; aa < 8; ++aa) Z[aa * 64 + (((M << 3) + P) ^ (aa << 3))] = y[aa];
  WAVE_LDS_FENCE();

  float2 yv[8];
#pragma unroll
  for (int u = 0; u < 8; ++u) yv[u] = Z[P * 64 + (((u << 3) + M) ^ (P << 3))];
  WAVE_LDS_FENCE();

  // ---- pass 3: 8-pt DFT over u; X[64b + t]
  float2 X[8];
  dft8(yv, X);
#pragma unroll
  for (int bb = 0; bb < 8; ++bb) Z[bb * 64 + t] = X[bb];
  WAVE_LDS_FENCE();

  // ---- power spectrum (real-FFT unpack), 513 bins ----
#pragma unroll
  for (int j = 0; j < 8; ++j) {
    int k = t + 64 * j;
    p[k] = powspec(Z, utw, k);
  }
  if (t == 0) p[512] = powspec(Z, utw, 512);
  WAVE_LDS_FENCE();

  // ---- sparse mel projection + log: 2 mels per lane ----
  float mv[2];
#pragma unroll
  for (int h = 0; h < 2; ++h) {
    int m = 2 * t + h;
    int2 sl = melsl[m];
    float acc = 0.f;
    const float* wrow = melw + m * MAXW;
    for (int j = 0; j < sl.y; ++j) acc = fmaf(p[sl.x + j], wrow[j], acc);
    mv[h] = logf(fmaxf(acc, 1e-5f));
  }
  ((float2*)(lm + (size_t)fr * NMEL))[t] = make_float2(mv[0], mv[1]);
}

// ---------------- conv-as-GEMM kernel ----------------
// out[m][n] = act( bias[n] + sum_k A[m][k] * wt[k][n] ),  k = dt*C + i,
// A[m][k] = in[(m + dt - 1)][i] with per-batch zero padding at t edges.
// TRANSOUT: write out[n][m] with row pitch PITCH (for VQ consumption).
template <int C, int N, bool GELU, bool TRANSOUT>
__global__ __launch_bounds__(256) void k_conv(const float* __restrict__ in,
                                              const float* __restrict__ wt,
                                              const float* __restrict__ bias,
                                              float* __restrict__ out) {
  constexpr int K = 3 * C;
  __shared__ float At[32 * 64];  // [kc][m]
  __shared__ float Bt[32 * 64];  // [kc][n]
  const int m0 = blockIdx.x * 64;
  const int n0 = blockIdx.y * 64;
  const int tid = threadIdx.x;
  const int tm = tid >> 4, tn = tid & 15;

  float acc[4][4] = {};

  const int ml = tid >> 2;          // staging row 0..63
  const int fi0 = tid & 3;
  const int mload = m0 + ml;
  const int bql = mload / TFR;
  const int tql = mload - bql * TFR;

  for (int k0 = 0; k0 < K; k0 += 32) {
    const int dt = k0 / C;
    const int i0 = k0 - dt * C;
    // stage A (transposed)
    {
      const int ttq = tql + dt - 1;
      const bool ok = (mload < MROWS) && (ttq >= 0) && (ttq < TFR);
      const float* rp = in + (size_t)(mload + dt - 1) * C + i0;
#pragma unroll
      for (int h = 0; h < 2; ++h) {
        const int fi = fi0 + h * 4;
        float4 v = ok ? *(const float4*)(rp + fi * 4) : make_float4(0.f, 0.f, 0.f, 0.f);
        At[(fi * 4 + 0) * 64 + ml] = v.x;
        At[(fi * 4 + 1) * 64 + ml] = v.y;
        At[(fi * 4 + 2) * 64 + ml] = v.z;
        At[(fi * 4 + 3) * 64 + ml] = v.w;
      }
    }
    // stage B
    {
#pragma unroll
      for (int h = 0; h < 2; ++h) {
        const int e = tid + h * 256;  // float4 id 0..511
        const int kc = e >> 4;
        const int nf = e & 15;
        float4 v = *(const float4*)(wt + (size_t)(k0 + kc) * N + n0 + nf * 4);
        *(float4*)&Bt[kc * 64 + nf * 4] = v;
      }
    }
    __syncthreads();
#pragma unroll
    for (int kc = 0; kc < 32; ++kc) {
      float4 a = *(const float4*)&At[kc * 64 + tm * 4];
      float4 bv = *(const float4*)&Bt[kc * 64 + tn * 4];
      float av[4] = {a.x, a.y, a.z, a.w};
      float bb[4] = {bv.x, bv.y, bv.z, bv.w};
#pragma unroll
      for (int r = 0; r < 4; ++r)
#pragma unroll
        for (int cq = 0; cq < 4; ++cq) acc[r][cq] = fmaf(av[r], bb[cq], acc[r][cq]);
    }
    __syncthreads();
  }

  if (TRANSOUT) {
#pragma unroll
    for (int cq = 0; cq < 4; ++cq) {
      const int n = n0 + tn * 4 + cq;
      const float bv = bias[n];
      float4 o = make_float4(acc[0][cq] + bv, acc[1][cq] + bv,
                             acc[2][cq] + bv, acc[3][cq] + bv);
      *(float4*)(out + (size_t)n * PITCH + m0 + tm * 4) = o;
    }
  } else {
#pragma unroll
    for (int r = 0; r < 4; ++r) {
      const int m = m0 + tm * 4 + r;
      if (m >= MROWS) continue;
      float4 o;
      float* ov = (float*)&o;
#pragma unroll
      for (int cq = 0; cq < 4; ++cq) {
        float v = acc[r][cq] + bias[n0 + tn * 4 + cq];
        if (GELU) v = 0.5f * v * (1.0f + erff(v * 0.7071067811865476f));
        ov[cq] = v;
      }
      *(float4*)(out + (size_t)m * N + n0 + tn * 4) = o;
    }
  }
}

// ---------------- VQ GEMM: 64m x 64v tiles, partial argmin per chunk ----------------
__global__ __launch_bounds__(256, 4) void k_vqg(const float* __restrict__ feT,
                                                const float* __restrict__ cbT,
                                                const float* __restrict__ c2,
                                                float2* __restrict__ pb) {
  __shared__ float At[32 * 64];  // [kc][m]
  __shared__ float Bt[32 * 64];  // [kc][v]
  __shared__ float x2s[64];

  const int m0 = blockIdx.x * 64;
  const int v0 = blockIdx.y * 64;
  const int cb = blockIdx.z;
  const int tid = threadIdx.x;
  const int tm = tid >> 4, tn = tid & 15;

  float acc[4][4] = {};
  float x2acc = 0.f;

  const float* fbase = feT + (size_t)(cb * 128) * PITCH + m0;
  const float* bbase = cbT + (size_t)(cb * 128) * 1024 + v0;

  for (int k0 = 0; k0 < 128; k0 += 32) {
    // stage A + B: linear float4 copies (both sources pre-transposed)
#pragma unroll
    for (int h = 0; h < 2; ++h) {
      const int id = tid + h * 256;           // 0..511
      const int row = id >> 4, col = (id & 15) * 4;
      *(float4*)&At[id * 4] = *(const float4*)(fbase + (size_t)(k0 + row) * PITCH + col);
      *(float4*)&Bt[id * 4] = *(const float4*)(bbase + (size_t)(k0 + row) * 1024 + col);
    }
    __syncthreads();
    // x2 partial (ascending k, matches prior rounds' order)
    if (tid < 64) {
#pragma unroll
      for (int kc = 0; kc < 32; ++kc) {
        float a = At[kc * 64 + tid];
        x2acc = fmaf(a, a, x2acc);
      }
    }
#pragma unroll
    for (int kc = 0; kc < 32; ++kc) {
      float4 a = *(const float4*)&At[kc * 64 + tm * 4];
      float4 bv = *(const float4*)&Bt[kc * 64 + tn * 4];
      float av[4] = {a.x, a.y, a.z, a.w};
      float bb[4] = {bv.x, bv.y, bv.z, bv.w};
#pragma unroll
      for (int r = 0; r < 4; ++r)
#pragma unroll
        for (int cq = 0; cq < 4; ++cq) acc[r][cq] = fmaf(av[r], bb[cq], acc[r][cq]);
    }
    __syncthreads();
  }

  if (tid < 64) x2s[tid] = x2acc;
  __syncthreads();

  // fused distance + per-thread argmin (cols ascending -> first-min kept)
  float best[4] = {FLT_MAX, FLT_MAX, FLT_MAX, FLT_MAX};
  int bidx[4] = {0, 0, 0, 0};
  float4 c24 = *(const float4*)(c2 + cb * 1024 + v0 + tn * 4);
  const float cc[4] = {c24.x, c24.y, c24.z, c24.w};
#pragma unroll
  for (int r = 0; r < 4; ++r) {
    const float x2v = x2s[tm * 4 + r];
#pragma unroll
    for (int cq = 0; cq < 4; ++cq) {
      const int n = v0 + tn * 4 + cq;
      const float d2 = x2v - 2.0f * acc[r][cq] + cc[cq];
      if (d2 < best[r]) { best[r] = d2; bidx[r] = n; }
    }
  }

  // per-row reduce across 16 tn (reuse At/Bt as scratch)
  float* redD = At;
  int* redI = (int*)Bt;
#pragma unroll
  for (int r = 0; r < 4; ++r) {
    redD[(tm * 4 + r) * 16 + tn] = best[r];
    redI[(tm * 4 + r) * 16 + tn] = bidx[r];
  }
  __syncthreads();
  if (tid < 64) {
    float bd = redD[tid * 16];
    int bi = redI[tid * 16];
#pragma unroll
    for (int j = 1; j < 16; ++j) {
      float d = redD[tid * 16 + j];
      int i2 = redI[tid * 16 + j];
      if (d < bd || (d == bd && i2 < bi)) { bd = d; bi = i2; }
    }
    pb[((size_t)(cb * 16 + blockIdx.y)) * PITCH + m0 + tid] = make_float2(bd, __int_as_float(bi));
  }
}

// ---------------- VQ chunk-reduce ----------------
__global__ void k_vqr(const float2* __restrict__ pb, int* __restrict__ out) {
  const int m = blockIdx.x * 256 + threadIdx.x;
  const int cb = blockIdx.y;
  if (m >= MROWS) return;
  float bd = FLT_MAX;
  int bi = 0;
  const float2* p = pb + (size_t)(cb * 16) * PITCH + m;
  for (int vc = 0; vc < 16; ++vc) {
    float2 e = p[(size_t)vc * PITCH];
    float d = e.x;
    int i2 = __float_as_int(e.y);
    if (d < bd) { bd = d; bi = i2; }   // ascending vc -> first-min (lowest idx) kept
  }
  const int b = m / TFR;
  const int t = m - b * TFR;
  out[((size_t)b * 4 + cb) * TFR + t] = bi;
}

// ---------------- launch ----------------
extern "C" void kernel_launch(void* const* d_in, const int* in_sizes, int n_in,
                              void* d_out, int out_size, void* d_ws, size_t ws_size,
                              hipStream_t stream) {
  if (ws_size < WS_NEEDED) return;  // fail visibly (out stays poisoned)

  const float* wav = (const float*)d_in[0];
  const float* w1 = (const float*)d_in[1];
  const float* b1 = (const float*)d_in[2];
  const float* w2 = (const float*)d_in[3];
  const float* b2 = (const float*)d_in[4];
  const float* cbs = (const float*)d_in[5];
  int* out = (int*)d_out;

  char* W = (char*)d_ws;
  float* win = (float*)(W + OFF_WIN);
  float2* tw512 = (float2*)(W + OFF_TW512);
  float2* utw = (float2*)(W + OFF_UTW);
  float* melw = (float*)(W + OFF_MELW);
  int2* melsl = (int2*)(W + OFF_MELSL);
  float* wb1 = (float*)(W + OFF_WB1);
  float* wb2 = (float*)(W + OFF_WB2);
  float* c2 = (float*)(W + OFF_C2);
  float* cbT = (float*)(W + OFF_CBT);
  float* h = (float*)(W + OFF_H);
  float2* pb = (float2*)(W + OFF_PB);
  float* lm = (float*)(W + OFF_LM);
  float* feT = (float*)(W + OFF_FET);

  k_setup_tab<<<1, 1024, 0, stream>>>(win, tw512, utw);
  k_melw<<<1, 128, 0, stream>>>(melw, melsl);
  k_wt<<<(256 * 128 * 3 + 255) / 256, 256, 0, stream>>>(w1, wb1, 256, 128);
  k_wt<<<(512 * 256 * 3 + 255) / 256, 256, 0, stream>>>(w2, wb2, 512, 256);
  k_c2<<<16, 256, 0, stream>>>(cbs, c2);
  k_cbt<<<2048, 256, 0, stream>>>(cbs, cbT);

  k_logmel2<<<3004, 256, 0, stream>>>(wav, win, tw512, utw, melw, melsl, lm);
  k_conv<128, 256, true, false><<<dim3(188, 4), 256, 0, stream>>>(lm, wb1, b1, h);
  k_conv<256, 512, false, true><<<dim3(188, 8), 256, 0, stream>>>(h, wb2, b2, feT);
  k_vqg<<<dim3(188, 16, 4), 256, 0, stream>>>(feT, cbT, c2, pb);
  k_vqr<<<dim3(47, 4), 256, 0, stream>>>(pb, out);
}